// Round 6
// baseline (1562.431 us; speedup 1.0000x reference)
//
#include <hip/hip_runtime.h>
#include <cstdint>

// Fused: out[n,o] = LN_o( -sum_i |x[n,i]*mbin[i] - w[i,o]| * mbout[o] ).
// N=4096 tokens, Cin=Cout=512, f32. VALU-bound (no fp32 MFMA; op isn't a MAC).
// R6: ONE kernel. Block = 16 rows x ALL 512 cols, 1024 threads = 16 waves =
// 4 waves/SIMD guaranteed (R0/R5 were stuck at ~2/SIMD, VALUBusy 64%).
// w-tile (32x512 = 64KB contiguous slab) double-buffered in dynamic LDS via
// global_load_lds width-16; x reg-staged (1 float/thread) with mbin folded.
// LN computed in-block (rows complete) -> kills the 60us LN kernel + round-trip.

constexpr int ROWS = 16;          // rows per block
constexpr int BK = 32;            // k per tile
constexpr int CIN = 512, COUT = 512;
constexpr int XS_STRIDE = BK + 1; // pad: x broadcast reads conflict-free

constexpr int WBUF_FLOATS = BK * COUT;          // 16384 (64KB)
constexpr int XS_FLOATS   = ROWS * XS_STRIDE;   // 528
constexpr int OFF_W0  = 0;
constexpr int OFF_W1  = WBUF_FLOATS;
constexpr int OFF_X0  = 2 * WBUF_FLOATS;
constexpr int OFF_X1  = OFF_X0 + XS_FLOATS;
constexpr int OFF_RED = OFF_X1 + XS_FLOATS;     // 16 waves x 16 rows x 2
constexpr int SMEM_BYTES = (OFF_RED + 16 * 16 * 2) * 4;   // 137,344 B

__device__ __forceinline__ void gload_lds16(const float* g, float* l) {
  __builtin_amdgcn_global_load_lds(
      (const __attribute__((address_space(1))) void*)g,
      (__attribute__((address_space(3))) void*)l, 16, 0, 0);
}

__global__ __launch_bounds__(1024, 4)
void adder_ln_fused(const float* __restrict__ x, const float* __restrict__ w,
                    const float* __restrict__ mbin, const float* __restrict__ mbout,
                    const float* __restrict__ gamma, const float* __restrict__ beta,
                    float* __restrict__ out) {
  extern __shared__ float smem[];
  float* const wb0 = smem + OFF_W0;
  float* const wb1 = smem + OFF_W1;
  float* const xb0 = smem + OFF_X0;
  float* const xb1 = smem + OFF_X1;
  float* const red = smem + OFF_RED;

  const int tid = threadIdx.x;
  const int r = tid & 15;          // row within block
  const int c = tid >> 4;          // col-group [0,64), 8 cols each
  const int bm = blockIdx.x * ROWS;

  // x staging ids (threads 0..511 stage the 16x32 x-tile)
  const int xr = tid >> 5, xk = tid & 31;

  float acc[8];
  #pragma unroll
  for (int j = 0; j < 8; ++j) acc[j] = 0.f;

  auto STAGE_W = [&](int k0, float* dst) {
    const float* src = w + (size_t)k0 * COUT;   // contiguous 64KB slab of w
    #pragma unroll
    for (int it = 0; it < 4; ++it) {
      const int fi = (it * 1024 + tid) * 4;     // float index, lane-linear
      gload_lds16(src + fi, dst + fi);
    }
  };

  // ---- prologue: tile 0
  STAGE_W(0, wb0);
  float xv = 0.f;
  if (tid < 512) {
    xv = x[(size_t)(bm + xr) * CIN + xk] * mbin[xk];
    xb0[xr * XS_STRIDE + xk] = xv;
  }
  __syncthreads();   // compiler drains vmcnt (gload_lds) + lgkm before barrier

  const int NT = CIN / BK;   // 16
  int cur = 0;
  for (int t = 0; t < NT; ++t) {
    float* const wcur = cur ? wb1 : wb0;
    float* const wnxt = cur ? wb0 : wb1;
    float* const xcur = cur ? xb1 : xb0;
    float* const xnxt = cur ? xb0 : xb1;

    if (t + 1 < NT) {
      STAGE_W((t + 1) * BK, wnxt);             // async, in flight under compute
      if (tid < 512)
        xv = x[(size_t)(bm + xr) * CIN + (t + 1) * BK + xk] * mbin[(t + 1) * BK + xk];
    }

    const float* wbase = wcur + c * 8;         // per-thread base; kk*512 is imm
    const float* xbase = xcur + r * XS_STRIDE;
    #pragma unroll
    for (int kk = 0; kk < BK; ++kk) {
      const float xsv = xbase[kk];                                        // b32 bcast
      const float4 w0 = *reinterpret_cast<const float4*>(wbase + kk * COUT);     // b128
      const float4 w1 = *reinterpret_cast<const float4*>(wbase + kk * COUT + 4); // b128
      acc[0] += fabsf(xsv - w0.x);
      acc[1] += fabsf(xsv - w0.y);
      acc[2] += fabsf(xsv - w0.z);
      acc[3] += fabsf(xsv - w0.w);
      acc[4] += fabsf(xsv - w1.x);
      acc[5] += fabsf(xsv - w1.y);
      acc[6] += fabsf(xsv - w1.z);
      acc[7] += fabsf(xsv - w1.w);
    }

    if (t + 1 < NT && tid < 512)
      xnxt[xr * XS_STRIDE + xk] = xv;          // xnxt last read pre-barrier: safe
    __syncthreads();
    cur ^= 1;
  }

  // ---- epilogue: y = -acc * mbout, then LayerNorm over the row (in-block)
  const float4 mo0 = *reinterpret_cast<const float4*>(&mbout[c * 8]);
  const float4 mo1 = *reinterpret_cast<const float4*>(&mbout[c * 8 + 4]);
  float y[8];
  y[0] = -acc[0] * mo0.x; y[1] = -acc[1] * mo0.y;
  y[2] = -acc[2] * mo0.z; y[3] = -acc[3] * mo0.w;
  y[4] = -acc[4] * mo1.x; y[5] = -acc[5] * mo1.y;
  y[6] = -acc[6] * mo1.z; y[7] = -acc[7] * mo1.w;

  float s = 0.f, s2 = 0.f;
  #pragma unroll
  for (int j = 0; j < 8; ++j) { s += y[j]; s2 = fmaf(y[j], y[j], s2); }

  // reduce over the wave's 4 c-groups (lanes r, r+16, r+32, r+48)
  s  += __shfl_xor(s, 16, 64);  s2 += __shfl_xor(s2, 16, 64);
  s  += __shfl_xor(s, 32, 64);  s2 += __shfl_xor(s2, 32, 64);

  const int wv = tid >> 6;      // wave id [0,16)
  const int lane = tid & 63;
  if (lane < 16) {              // lane == its row r
    red[(wv * 16 + lane) * 2 + 0] = s;
    red[(wv * 16 + lane) * 2 + 1] = s2;
  }
  __syncthreads();

  float S = 0.f, S2 = 0.f;
  #pragma unroll
  for (int w2 = 0; w2 < 16; ++w2) {
    S  += red[(w2 * 16 + r) * 2 + 0];
    S2 += red[(w2 * 16 + r) * 2 + 1];
  }
  const float mean = S * (1.0f / 512.0f);
  const float var  = S2 * (1.0f / 512.0f) - mean * mean;  // one-pass; err ~8e-3 ok
  const float rstd = rsqrtf(var + 1e-5f);

  const float4 g0 = *reinterpret_cast<const float4*>(&gamma[c * 8]);
  const float4 g1 = *reinterpret_cast<const float4*>(&gamma[c * 8 + 4]);
  const float4 b0 = *reinterpret_cast<const float4*>(&beta[c * 8]);
  const float4 b1 = *reinterpret_cast<const float4*>(&beta[c * 8 + 4]);

  float4 o0, o1;
  o0.x = (y[0] - mean) * rstd * g0.x + b0.x;
  o0.y = (y[1] - mean) * rstd * g0.y + b0.y;
  o0.z = (y[2] - mean) * rstd * g0.z + b0.z;
  o0.w = (y[3] - mean) * rstd * g0.w + b0.w;
  o1.x = (y[4] - mean) * rstd * g1.x + b1.x;
  o1.y = (y[5] - mean) * rstd * g1.y + b1.y;
  o1.z = (y[6] - mean) * rstd * g1.z + b1.z;
  o1.w = (y[7] - mean) * rstd * g1.w + b1.w;

  float* dst = out + (size_t)(bm + r) * COUT + c * 8;
  *reinterpret_cast<float4*>(dst)     = o0;
  *reinterpret_cast<float4*>(dst + 4) = o1;
}

extern "C" void kernel_launch(void* const* d_in, const int* in_sizes, int n_in,
                              void* d_out, int out_size, void* d_ws, size_t ws_size,
                              hipStream_t stream) {
  const float* x     = (const float*)d_in[0];
  const float* w     = (const float*)d_in[1];
  const float* mbin  = (const float*)d_in[2];
  const float* mbout = (const float*)d_in[3];
  const float* gamma = (const float*)d_in[4];
  const float* beta  = (const float*)d_in[5];
  float* out = (float*)d_out;

  const int Cin = in_sizes[2];          // 512
  const int N   = in_sizes[0] / Cin;    // 4096 tokens

  // >64KB dynamic LDS needs the attribute (idempotent, capture-safe host call)
  hipFuncSetAttribute((const void*)adder_ln_fused,
                      hipFuncAttributeMaxDynamicSharedMemorySize, SMEM_BYTES);

  adder_ln_fused<<<dim3(N / ROWS), 1024, SMEM_BYTES, stream>>>(
      x, w, mbin, mbout, gamma, beta, out);
}